// Round 1
// baseline (2457.148 us; speedup 1.0000x reference)
//
#include <hip/hip_runtime.h>
#include <stdint.h>

// ---------------------------------------------------------------------------
// LSTM-VAE persistent kernel, MI355X (gfx950).  B=128, T=512, I=L=64, H=512,
// 100 decoder steps.  fp32 in/out; bf16 MFMA internal.
//
// 128 WGs = 8 batch-groups(g) x 16 hidden-slices(s), block=512 (8 waves).
// Slice owns 32 hidden dims = 128 interleaved gate rows [i0,f0,g0,o0,...];
// W_hh slice in 64 VGPRs/lane as MFMA B-fragments. Decoder folds x_hat via
// W_comb = W_hh_dec + W_ih_dec@W_out; x_hat tiles on wave 7 of slices 0-3.
//
// Round-9 sync: POLL-ON-DATA phase-bit protocol (replaces r5/r8 flags).
// Every published value is h = sigmoid*tanh with |h| <= 1.0, so bit14
// (exponent MSB) of each bf16 is always 0.  Round R writes buf[R&1] with
// each bf16 XOR'd by (phase(R) ? 0x4000 : 0); phase alternates on every
// reuse of a buffer.  Consumers poll their own 32B chunk until EVERY bf16
// carries the round's phase bit -- torn arrival keeps polling (no store
// atomicity assumed); stale-data collision is impossible (stale phase is
// always the complement).  This removes, per step: producer vmcnt(0)
// drain, the flag store, the flag-poll round trip, and one barrier -- the
// data load IS the poll.  Overwrite safety: unchanged depth-2 transitive
// certification (publishing R+1 follows staging R, so "all published R+1"
// => "all consumed R" => buf[R&1] reusable at R+2).  Round 513 (h_dec0,
// computed locally per-WG) is never published, so decoder rounds >=514 use
// a shifted phase formula (verified: every buffer reuse alternates phase).
// hbuf1 pre-filled with 0x40 bytes (bit14=1) so round 1 (phase 0) cannot
// false-trigger on uninitialized ws.  Flags retained ONLY for the one-shot
// z exchange (fp32 z is unbounded -> phase trick inapplicable there).
// Decoder stages take a leading guard barrier (xhat_emit reads Al after
// publish); encoder runs 2 barriers/step.
// ---------------------------------------------------------------------------

typedef short short8 __attribute__((ext_vector_type(8)));
typedef float f32x4 __attribute__((ext_vector_type(4)));
typedef unsigned int u32x4 __attribute__((ext_vector_type(4)));

#define WS_FLAGS  0           // 8 g x 16 s x 128 B (z exchange only)
#define WS_HBUF0  16384       // 128 KB
#define WS_HBUF1  147456      // 128 KB
#define WS_Z      278528      // 32 KB fp32
#define WS_BCOMB  311296      // 8 KB fp32
#define WS_WCOMB  319488      // 2 MB bf16
#define WS_SEQB   2416640     // 8 MB bf16 seq
#define WS_END    10805248
#define WS_ZERO   WS_HBUF1    // memset flags + hbuf0 (h0 = 0, phase 0)
#define HB1_SIZE  131072      // hbuf1: fill 0x40 (bit14=1, != phase 0)

static __device__ __forceinline__ float b2f(unsigned short u) {
    return __builtin_bit_cast(float, (unsigned int)u << 16);
}
static __device__ __forceinline__ unsigned short f2b(float f) {
    unsigned int u = __builtin_bit_cast(unsigned int, f);
    unsigned int r = u + 0x7FFFu + ((u >> 16) & 1u);  // RNE
    return (unsigned short)(r >> 16);
}
static __device__ __forceinline__ float sigm(float x)  { return 1.0f / (1.0f + __expf(-x)); }
static __device__ __forceinline__ float tanhx(float x) { return 1.0f - 2.0f / (__expf(2.0f * x) + 1.0f); }

static __device__ __forceinline__ short8 cvt8(const float* p) {
    const float4 a = ((const float4*)p)[0];
    const float4 b = ((const float4*)p)[1];
    short8 r;
    r[0] = (short)f2b(a.x); r[1] = (short)f2b(a.y);
    r[2] = (short)f2b(a.z); r[3] = (short)f2b(a.w);
    r[4] = (short)f2b(b.x); r[5] = (short)f2b(b.y);
    r[6] = (short)f2b(b.z); r[7] = (short)f2b(b.w);
    return r;
}

// phase(R): which XOR mask round R's buffer copy carries.  Encoder/VAE
// rounds 0..512: (R>>1)&1  (buf0 holds 0,2,4.. -> 0,1,0..; buf1 holds
// 1,3,5.. -> 0,1,0..).  Round 513 skipped (local h_dec0).  Decoder rounds
// 514..613: shifted so every buffer reuse still alternates:
//   514:1 515:0 516:0 517:1 518:1 519:0 ...
//   buf0: 512(0),514(1),516(0),518(1).. OK   buf1: 511(1),515(0),517(1).. OK
static __device__ __forceinline__ uint32_t phase_of(uint32_t R) {
    return (R <= 512u) ? ((R >> 1) & 1u)
                       : ((((R - 513u) >> 1) & 1u) ^ 1u);
}

// --- coherent (LLC-served, L1/L2-bypass) coalesced ops: sc0 sc1 ----------
static __device__ __forceinline__ void load2x16_cc(const void* p0, const void* p1,
                                                   u32x4& v0, u32x4& v1) {
    asm volatile("global_load_dwordx4 %0, %2, off sc0 sc1\n\t"
                 "global_load_dwordx4 %1, %3, off sc0 sc1\n\t"
                 "s_waitcnt vmcnt(0)"
                 : "=&v"(v0), "=&v"(v1) : "v"(p0), "v"(p1) : "memory");
}
static __device__ __forceinline__ void store16_cc(void* p, u32x4 v) {
    asm volatile("global_store_dwordx4 %0, %1, off sc0 sc1"
                 :: "v"(p), "v"(v) : "memory");
}
static __device__ __forceinline__ void drain_vm() {
    asm volatile("s_waitcnt vmcnt(0)" ::: "memory");
}

// ---------------------------------------------------------------------------
// Prologue A: seq fp32 -> bf16
// ---------------------------------------------------------------------------
__global__ void __launch_bounds__(256)
seqcvt_kernel(const float* __restrict__ src, unsigned short* __restrict__ dst)
{
    int i = (blockIdx.x * 256 + threadIdx.x) * 4;
    float4 v = *(const float4*)(src + i);
    uint32_t lo = (uint32_t)f2b(v.x) | ((uint32_t)f2b(v.y) << 16);
    uint32_t hi = (uint32_t)f2b(v.z) | ((uint32_t)f2b(v.w) << 16);
    uint2 o; o.x = lo; o.y = hi;
    *(uint2*)(dst + i) = o;
}

// ---------------------------------------------------------------------------
// Prologue B: W_comb = W_hh_dec + W_ih_dec @ W_out (bf16 out), b_comb (fp32)
// ---------------------------------------------------------------------------
__global__ void __launch_bounds__(256)
wcomb_kernel(const float* __restrict__ Wih_d,
             const float* __restrict__ Whh_d,
             const float* __restrict__ Wout,
             const float* __restrict__ bih_d,
             const float* __restrict__ bhh_d,
             const float* __restrict__ bout,
             unsigned char* __restrict__ ws)
{
    __shared__ float Ash[64][64];
    __shared__ float Bsh[64][65];
    const int bid = blockIdx.x, t = threadIdx.x;
    const int gt0 = (bid >> 3) * 64, ht0 = (bid & 7) * 64;
    for (int j = 0; j < 16; ++j) {
        int idx = t + j * 256;
        int r = idx >> 6, c = idx & 63;
        Ash[r][c] = Wih_d[(size_t)(gt0 + r) * 64 + c];
        Bsh[r][c] = Wout[(size_t)r * 512 + ht0 + c];
    }
    __syncthreads();
    const int gl = t >> 2, hl0 = (t & 3) * 16;
    for (int hh = 0; hh < 16; ++hh) {
        float acc = 0.f;
        #pragma unroll
        for (int i = 0; i < 64; ++i) acc += Ash[gl][i] * Bsh[i][hl0 + hh];
        int g = gt0 + gl, h = ht0 + hl0 + hh;
        float v = Whh_d[(size_t)g * 512 + h] + acc;
        ((unsigned short*)(ws + WS_WCOMB))[(size_t)g * 512 + h] = f2b(v);
    }
    if ((bid & 7) == 0 && t < 64) {
        int g = gt0 + t;
        float acc = bih_d[g] + bhh_d[g];
        #pragma unroll
        for (int i = 0; i < 64; ++i) acc += bout[i] * Ash[t][i];
        ((float*)(ws + WS_BCOMB))[g] = acc;
    }
}

// ---------------------------------------------------------------------------
// Main persistent kernel
// ---------------------------------------------------------------------------
__global__ void __launch_bounds__(512, 2)
vae_persistent(const float* __restrict__ seq,
               const unsigned short* __restrict__ seqb,
               const float* __restrict__ eps,
               const float* __restrict__ Wih_e,
               const float* __restrict__ Whh_e,
               const float* __restrict__ bih_e,
               const float* __restrict__ bhh_e,
               const float* __restrict__ Wmean,
               const float* __restrict__ bmean,
               const float* __restrict__ Wlv,
               const float* __restrict__ blv,
               const float* __restrict__ Winit,
               const float* __restrict__ binit,
               const float* __restrict__ Whh_d,
               const float* __restrict__ bih_d,
               const float* __restrict__ bhh_d,
               const float* __restrict__ Wout,
               const float* __restrict__ bout,
               unsigned char* __restrict__ ws,
               float* __restrict__ out)
{
    __shared__ __align__(16) short Al[16 * 520];  // staged h tile (bf16)
    __shared__ __align__(16) short Ho[512];       // h write-back staging [16][32]
    __shared__ float fbuf[128];                   // mean/logvar scratch
    __shared__ float zl[16 * 64];                 // z tile (fp32)

    const int tid  = threadIdx.x;
    const int g    = blockIdx.x & 7;        // batch group
    const int s    = blockIdx.x >> 3;       // hidden slice
    const int b0   = g * 16;
    const int lane = tid & 63;
    const int wv   = tid >> 6;
    const int col  = lane & 15;
    const int q    = lane >> 4;
    const int nloc = wv * 16 + col;
    const int gt   = nloc & 3;              // 0=i,1=f,2=g,3=o
    const int grow = gt * 512 + s * 32 + (nloc >> 2);

    uint32_t* flags = (uint32_t*)(ws + WS_FLAGS) + (size_t)g * 512;  // z only
    unsigned char* hbuf0 = ws + WS_HBUF0;
    unsigned char* hbuf1 = ws + WS_HBUF1;
    uint32_t* zbuf = (uint32_t*)(ws + WS_Z);

    float cst[4] = {0.f, 0.f, 0.f, 0.f};

    // ---- stage round R: every thread POLLS its own 32B until all 16 bf16
    //      carry phase(R), then decodes (XOR) and drops into Al. -----------
    auto wait_and_stage = [&](uint32_t R, bool guard) {
        if (guard) __syncthreads();            // decoder: xhat still reads Al
        const unsigned char* src = (R & 1) ? hbuf1 : hbuf0;
        const uint32_t pm = phase_of(R) ? 0x40004000u : 0u;
        const int b = tid >> 5, c = tid & 31;  // 16 rows x 32 chunks of 32 B
        const unsigned char* p0 = src + (size_t)(b0 + b) * 1024 + c * 32;
        u32x4 v0, v1;
        for (;;) {
            load2x16_cc(p0, p0 + 16, v0, v1);
            uint32_t acc = 0;
            #pragma unroll
            for (int i = 0; i < 4; ++i) {
                acc |= (v0[i] & 0x40004000u) ^ pm;
                acc |= (v1[i] & 0x40004000u) ^ pm;
            }
            if (acc == 0) break;
        }
        #pragma unroll
        for (int i = 0; i < 4; ++i) { v0[i] ^= pm; v1[i] ^= pm; }
        u32x4* dst = (u32x4*)Al;               // row stride 65 u32x4 = 520 shorts
        dst[b * 65 + c * 2 + 0] = v0;
        dst[b * 65 + c * 2 + 1] = v1;
        __syncthreads();
    };

    // ---- publish round R (wave 0: phase-tagged stores, NO drain/flag) ----
    auto publish_h = [&](uint32_t R) {
        if (wv == 0) {
            unsigned char* dst = (R & 1) ? hbuf1 : hbuf0;
            const uint32_t pm = phase_of(R) ? 0x40004000u : 0u;
            int row = lane >> 2, part = lane & 3;          // 16 B per lane
            u32x4 v = ((const u32x4*)Ho)[lane];
            #pragma unroll
            for (int i = 0; i < 4; ++i) v[i] ^= pm;
            store16_cc(dst + (size_t)(b0 + row) * 1024 + s * 64 + part * 16, v);
        }
    };

    short8 wfrag[16];
    auto load_wfrag_f32 = [&](const float* Wsrc) {
        #pragma unroll
        for (int kt = 0; kt < 16; ++kt)
            wfrag[kt] = cvt8(Wsrc + (size_t)grow * 512 + kt * 32 + q * 8);
    };
    auto load_wfrag_bf16 = [&](const unsigned short* Wsrc) {
        #pragma unroll
        for (int kt = 0; kt < 16; ++kt)
            wfrag[kt] = *(const short8*)((const short*)Wsrc +
                         (size_t)grow * 512 + kt * 32 + q * 8);
    };

    // activations + cell update; h slice left in Ho (sync before publish)
    auto cell_update = [&](f32x4 acc) {
        float act[4];
        #pragma unroll
        for (int r = 0; r < 4; ++r)
            act[r] = (gt == 2) ? tanhx(acc[r]) : sigm(acc[r]);
        int base = lane & ~3;
        #pragma unroll
        for (int r = 0; r < 4; ++r) {
            float vi = __shfl(act[r], base + 0);
            float vf = __shfl(act[r], base + 1);
            float vg = __shfl(act[r], base + 2);
            float vo = __shfl(act[r], base + 3);
            cst[r] = vf * cst[r] + vi * vg;
            act[r] = vo * tanhx(cst[r]);
        }
        if (gt == 0) {
            int hd4 = wv * 4 + (col >> 2);     // 0..31
            #pragma unroll
            for (int r = 0; r < 4; ++r)
                Ho[(q * 4 + r) * 32 + hd4] = (short)f2b(act[r]);
        }
    };

    // ---------------- encoder: 512 steps ----------------
    load_wfrag_f32(Whh_e);
    short8 xwf[2];
    #pragma unroll
    for (int kt = 0; kt < 2; ++kt)
        xwf[kt] = cvt8(Wih_e + (size_t)grow * 64 + kt * 32 + q * 8);
    const float bias_e = bih_e[grow] + bhh_e[grow];

    auto load_x = [&](int t, short8* xf) {
        if (seqb) {
            const short* xs = (const short*)seqb + ((size_t)(b0 + col) * 512 + t) * 64 + q * 8;
            xf[0] = *(const short8*)(xs);
            xf[1] = *(const short8*)(xs + 32);
        } else {
            const float* xs = seq + ((size_t)(b0 + col) * 512 + t) * 64 + q * 8;
            xf[0] = cvt8(xs);
            xf[1] = cvt8(xs + 32);
        }
    };

    short8 xf[2];
    load_x(0, xf);
    for (uint32_t t = 0; t < 512; ++t) {
        wait_and_stage(t, false);            // t=0: hbuf0 zeros, phase 0 -> instant
        f32x4 acc = {bias_e, bias_e, bias_e, bias_e};
        acc = __builtin_amdgcn_mfma_f32_16x16x32_bf16(xf[0], xwf[0], acc, 0, 0, 0);
        acc = __builtin_amdgcn_mfma_f32_16x16x32_bf16(xf[1], xwf[1], acc, 0, 0, 0);
        if (t < 511) load_x(t + 1, xf);
        #pragma unroll
        for (int kt = 0; kt < 16; ++kt) {
            short8 a = *(const short8*)(Al + col * 520 + kt * 32 + q * 8);
            acc = __builtin_amdgcn_mfma_f32_16x16x32_bf16(a, wfrag[kt], acc, 0, 0, 0);
        }
        cell_update(acc);
        __syncthreads();
        publish_h(t + 1);                    // h_{t+1} -> round t+1
    }

    // ---------------- VAE reparameterization (flag 513 = z ready) ---------
    wait_and_stage(512, false);              // Al = h_n
    if (tid < 128) {
        int which = tid >> 6, idx = tid & 63;
        int b = idx >> 2, ldl = idx & 3;
        int ld = s * 4 + ldl;
        const float* wrow = (which ? Wlv : Wmean) + (size_t)ld * 512;
        float a = (which ? blv[ld] : bmean[ld]);
        for (int k = 0; k < 512; ++k)
            a += b2f((unsigned short)Al[b * 520 + k]) * wrow[k];
        out[819200 + which * 8192 + (size_t)(b0 + b) * 64 + ld] = a;
        fbuf[which * 64 + idx] = a;
    }
    __syncthreads();
    if (wv == 0) {
        int b = lane >> 2, ldl = lane & 3;
        int ld = s * 4 + ldl;
        float m = fbuf[lane], lv = fbuf[64 + lane];
        float e = eps[(size_t)(b0 + b) * 64 + ld];
        float z = m + e * __expf(0.5f * lv);
        __hip_atomic_store(zbuf + (size_t)(b0 + b) * 64 + ld,
                           __builtin_bit_cast(uint32_t, z),
                           __ATOMIC_RELAXED, __HIP_MEMORY_SCOPE_AGENT);
        drain_vm();
        if (lane == 0)
            __hip_atomic_store(&flags[s * 32], 513u,
                               __ATOMIC_RELAXED, __HIP_MEMORY_SCOPE_AGENT);
    }
    if (wv == 0 && lane < 16)
        while (__hip_atomic_load(&flags[lane * 32], __ATOMIC_RELAXED,
                                 __HIP_MEMORY_SCOPE_AGENT) < 513u) {}
    __syncthreads();

    // h_dec0 = z @ W_init^T + b_init, computed locally into Al
    #pragma unroll
    for (int j = 0; j < 2; ++j) {
        int idx = tid + j * 512;
        int b = idx >> 6, l = idx & 63;
        uint32_t v = __hip_atomic_load(zbuf + (size_t)(b0 + b) * 64 + l,
                                       __ATOMIC_RELAXED, __HIP_MEMORY_SCOPE_AGENT);
        zl[b * 64 + l] = __builtin_bit_cast(float, v);
    }
    __syncthreads();
    {
        int b = tid >> 5, c = tid & 31;
        #pragma unroll
        for (int j = 0; j < 16; ++j) {
            int hd = c * 16 + j;
            float a = binit[hd];
            const float* wr = Winit + (size_t)hd * 64;
            #pragma unroll
            for (int l = 0; l < 64; ++l) a += zl[b * 64 + l] * wr[l];
            Al[b * 520 + hd] = (short)f2b(a);
        }
    }
    #pragma unroll
    for (int r = 0; r < 4; ++r) cst[r] = 0.f;
    __syncthreads();

    // -------- decoder: 100 steps; step d publishes h_{d+1} as R=514+d -----
    short8 wof[16];
    float xbias = 0.f;
    if (s < 4 && wv == 7) {                  // x_hat tile s on wave 7 (no duties)
        xbias = bout[s * 16 + col];
        #pragma unroll
        for (int kt = 0; kt < 16; ++kt)
            wof[kt] = cvt8(Wout + (size_t)(s * 16 + col) * 512 + kt * 32 + q * 8);
    }
    auto xhat_emit = [&](int d) {            // x_hat_d from Al (= h_{d+1})
        f32x4 a2 = {xbias, xbias, xbias, xbias};
        #pragma unroll
        for (int kt = 0; kt < 16; ++kt) {
            short8 a = *(const short8*)(Al + col * 520 + kt * 32 + q * 8);
            a2 = __builtin_amdgcn_mfma_f32_16x16x32_bf16(a, wof[kt], a2, 0, 0, 0);
        }
        #pragma unroll
        for (int r = 0; r < 4; ++r) {
            int b = q * 4 + r;
            out[((size_t)(b0 + b) * 100 + d) * 64 + s * 16 + col] = a2[r];
        }
    };

    load_wfrag_f32(Whh_d);                   // step 0: x0 == 0
    float bias = bih_d[grow] + bhh_d[grow];
    for (uint32_t d = 0; d < 100; ++d) {
        if (d > 0) wait_and_stage(513 + d, true);  // Al = h_d
        f32x4 acc = {bias, bias, bias, bias};
        #pragma unroll
        for (int kt = 0; kt < 16; ++kt) {
            short8 a = *(const short8*)(Al + col * 520 + kt * 32 + q * 8);
            acc = __builtin_amdgcn_mfma_f32_16x16x32_bf16(a, wfrag[kt], acc, 0, 0, 0);
        }
        cell_update(acc);
        __syncthreads();
        publish_h(514 + d);
        if (d >= 1 && s < 4 && wv == 7) xhat_emit(d - 1);   // off critical path
        if (d == 0) {
            load_wfrag_bf16((const unsigned short*)(ws + WS_WCOMB));
            bias = ((const float*)(ws + WS_BCOMB))[grow];
        }
    }
    wait_and_stage(613, true);               // Al = h_100
    if (s < 4 && wv == 7) xhat_emit(99);
}

extern "C" void kernel_launch(void* const* d_in, const int* in_sizes, int n_in,
                              void* d_out, int out_size, void* d_ws, size_t ws_size,
                              hipStream_t stream) {
    (void)in_sizes; (void)n_in; (void)out_size;
    const float* seq   = (const float*)d_in[0];
    const float* eps   = (const float*)d_in[2];
    const float* Wih_e = (const float*)d_in[3];
    const float* Whh_e = (const float*)d_in[4];
    const float* bih_e = (const float*)d_in[5];
    const float* bhh_e = (const float*)d_in[6];
    const float* Wmean = (const float*)d_in[7];
    const float* bmean = (const float*)d_in[8];
    const float* Wlv   = (const float*)d_in[9];
    const float* blv   = (const float*)d_in[10];
    const float* Winit = (const float*)d_in[11];
    const float* binit = (const float*)d_in[12];
    const float* Wih_d = (const float*)d_in[13];
    const float* Whh_d = (const float*)d_in[14];
    const float* bih_d = (const float*)d_in[15];
    const float* bhh_d = (const float*)d_in[16];
    const float* Wout  = (const float*)d_in[17];
    const float* bout  = (const float*)d_in[18];
    unsigned char* ws = (unsigned char*)d_ws;
    float* out = (float*)d_out;

    const bool have_seqb = ws_size >= (size_t)WS_END;
    unsigned short* seqb = have_seqb ? (unsigned short*)(ws + WS_SEQB) : nullptr;

    hipMemsetAsync(ws, 0, WS_ZERO, stream);            // flags + hbuf0 (phase 0)
    hipMemsetAsync(ws + WS_HBUF1, 0x40, HB1_SIZE, stream);  // hbuf1: bit14=1
    if (have_seqb)
        seqcvt_kernel<<<4096, 256, 0, stream>>>(seq, seqb);
    wcomb_kernel<<<256, 256, 0, stream>>>(Wih_d, Whh_d, Wout, bih_d, bhh_d, bout, ws);
    vae_persistent<<<128, 512, 0, stream>>>(
        seq, seqb, eps, Wih_e, Whh_e, bih_e, bhh_e,
        Wmean, bmean, Wlv, blv, Winit, binit,
        Whh_d, bih_d, bhh_d, Wout, bout, ws, out);
}

// Round 2
// 1800.365 us; speedup vs baseline: 1.3648x; 1.3648x over previous
//
#include <hip/hip_runtime.h>
#include <stdint.h>

// ---------------------------------------------------------------------------
// LSTM-VAE persistent kernel, MI355X (gfx950).  B=128, T=512, I=L=64, H=512,
// 100 decoder steps.  fp32 in/out; bf16 MFMA internal.
//
// 128 WGs = 8 batch-groups(g) x 16 hidden-slices(s), block=512 (8 waves).
// Slice owns 32 hidden dims = 128 interleaved gate rows [i0,f0,g0,o0,...];
// W_hh slice in 64 VGPRs/lane as MFMA B-fragments. Decoder folds x_hat via
// W_comb = W_hh_dec + W_ih_dec@W_out; x_hat tiles on wave 7 of slices 0-3.
//
// Round-10 sync: POLL-ON-DATA phase-bit protocol (r9) + contention control.
// r9 post-mortem: 64K threads spinning coherent 32B loads = ~11 TB/s of poll
// traffic -> fabric saturation, delayed store visibility, 43ms outlier.
// r10: (a) one-shot first load (steady-state race is ~50/50) + s_sleep
// backoff on retries (64..512 cy), satisfied lanes exit the loop and stop
// loading; (b) XOR bank-swizzle of the Al staging tile: unit u (16B) of row
// r lives at u^((u>>3)&7) -> stage ds_write_b128 lanes land on 8 distinct
// 4-bank groups (was 8-way conflict, 5.5e7 conflict cycles); (c) x-MFMAs +
// x prefetch hoisted before the poll in the encoder.
//
// Phase protocol (unchanged from r9, verified): |h|<=1 so bit14 of every
// bf16 is 0.  Round R writes buf[R&1] with bf16s XOR'd by phase(R)<<14;
// phase alternates on every reuse of a buffer; consumers poll their own
// 32B chunk until EVERY bf16 carries phase(R).  Dword-atomic stores => a
// dword with correct phase bits is entirely from round R.  No producer
// drain, no flags (flags kept only for the one-shot fp32 z exchange).
// Overwrite safety: depth-2 transitive certification (publishing R+1
// follows staging R).  Round 513 (h_dec0) is local -> shifted decoder
// phase formula.  hbuf1 pre-filled 0x40 so round 1 can't false-trigger.
// ---------------------------------------------------------------------------

typedef short short8 __attribute__((ext_vector_type(8)));
typedef float f32x4 __attribute__((ext_vector_type(4)));
typedef unsigned int u32x4 __attribute__((ext_vector_type(4)));

#define WS_FLAGS  0           // 8 g x 16 s x 128 B (z exchange only)
#define WS_HBUF0  16384       // 128 KB
#define WS_HBUF1  147456      // 128 KB
#define WS_Z      278528      // 32 KB fp32
#define WS_BCOMB  311296      // 8 KB fp32
#define WS_WCOMB  319488      // 2 MB bf16
#define WS_SEQB   2416640     // 8 MB bf16 seq
#define WS_END    10805248
#define WS_ZERO   WS_HBUF1    // memset flags + hbuf0 (h0 = 0, phase 0)
#define HB1_SIZE  131072      // hbuf1: fill 0x40 (bit14=1, != phase 0)

static __device__ __forceinline__ float b2f(unsigned short u) {
    return __builtin_bit_cast(float, (unsigned int)u << 16);
}
static __device__ __forceinline__ unsigned short f2b(float f) {
    unsigned int u = __builtin_bit_cast(unsigned int, f);
    unsigned int r = u + 0x7FFFu + ((u >> 16) & 1u);  // RNE
    return (unsigned short)(r >> 16);
}
static __device__ __forceinline__ float sigm(float x)  { return 1.0f / (1.0f + __expf(-x)); }
static __device__ __forceinline__ float tanhx(float x) { return 1.0f - 2.0f / (__expf(2.0f * x) + 1.0f); }

static __device__ __forceinline__ short8 cvt8(const float* p) {
    const float4 a = ((const float4*)p)[0];
    const float4 b = ((const float4*)p)[1];
    short8 r;
    r[0] = (short)f2b(a.x); r[1] = (short)f2b(a.y);
    r[2] = (short)f2b(a.z); r[3] = (short)f2b(a.w);
    r[4] = (short)f2b(b.x); r[5] = (short)f2b(b.y);
    r[6] = (short)f2b(b.z); r[7] = (short)f2b(b.w);
    return r;
}

// phase(R): encoder/VAE rounds 0..512: (R>>1)&1.  Round 513 skipped (local
// h_dec0).  Decoder rounds 514..613 shifted so every buffer reuse still
// alternates (buf0: 512(0),514(1),516(0)..; buf1: 511(1),515(0),517(1)..).
static __device__ __forceinline__ uint32_t phase_of(uint32_t R) {
    return (R <= 512u) ? ((R >> 1) & 1u)
                       : ((((R - 513u) >> 1) & 1u) ^ 1u);
}

// LDS bank swizzle for the Al tile: 16B unit u of a row is stored at
// alperm(u).  Bijective (keeps u>>3, XORs it into low bits); spreads the
// 8 lanes that used to share a 4-bank group across all 8 groups.
static __device__ __forceinline__ int alperm(int u) { return u ^ ((u >> 3) & 7); }

// --- coherent (LLC-served, L2-bypass) coalesced ops: sc0 sc1 -------------
static __device__ __forceinline__ void load2x16_cc(const void* p0, const void* p1,
                                                   u32x4& v0, u32x4& v1) {
    asm volatile("global_load_dwordx4 %0, %2, off sc0 sc1\n\t"
                 "global_load_dwordx4 %1, %3, off sc0 sc1\n\t"
                 "s_waitcnt vmcnt(0)"
                 : "=&v"(v0), "=&v"(v1) : "v"(p0), "v"(p1) : "memory");
}
static __device__ __forceinline__ void store16_cc(void* p, u32x4 v) {
    asm volatile("global_store_dwordx4 %0, %1, off sc0 sc1"
                 :: "v"(p), "v"(v) : "memory");
}
static __device__ __forceinline__ void drain_vm() {
    asm volatile("s_waitcnt vmcnt(0)" ::: "memory");
}

// ---------------------------------------------------------------------------
// Prologue A: seq fp32 -> bf16
// ---------------------------------------------------------------------------
__global__ void __launch_bounds__(256)
seqcvt_kernel(const float* __restrict__ src, unsigned short* __restrict__ dst)
{
    int i = (blockIdx.x * 256 + threadIdx.x) * 4;
    float4 v = *(const float4*)(src + i);
    uint32_t lo = (uint32_t)f2b(v.x) | ((uint32_t)f2b(v.y) << 16);
    uint32_t hi = (uint32_t)f2b(v.z) | ((uint32_t)f2b(v.w) << 16);
    uint2 o; o.x = lo; o.y = hi;
    *(uint2*)(dst + i) = o;
}

// ---------------------------------------------------------------------------
// Prologue B: W_comb = W_hh_dec + W_ih_dec @ W_out (bf16 out), b_comb (fp32)
// ---------------------------------------------------------------------------
__global__ void __launch_bounds__(256)
wcomb_kernel(const float* __restrict__ Wih_d,
             const float* __restrict__ Whh_d,
             const float* __restrict__ Wout,
             const float* __restrict__ bih_d,
             const float* __restrict__ bhh_d,
             const float* __restrict__ bout,
             unsigned char* __restrict__ ws)
{
    __shared__ float Ash[64][64];
    __shared__ float Bsh[64][65];
    const int bid = blockIdx.x, t = threadIdx.x;
    const int gt0 = (bid >> 3) * 64, ht0 = (bid & 7) * 64;
    for (int j = 0; j < 16; ++j) {
        int idx = t + j * 256;
        int r = idx >> 6, c = idx & 63;
        Ash[r][c] = Wih_d[(size_t)(gt0 + r) * 64 + c];
        Bsh[r][c] = Wout[(size_t)r * 512 + ht0 + c];
    }
    __syncthreads();
    const int gl = t >> 2, hl0 = (t & 3) * 16;
    for (int hh = 0; hh < 16; ++hh) {
        float acc = 0.f;
        #pragma unroll
        for (int i = 0; i < 64; ++i) acc += Ash[gl][i] * Bsh[i][hl0 + hh];
        int g = gt0 + gl, h = ht0 + hl0 + hh;
        float v = Whh_d[(size_t)g * 512 + h] + acc;
        ((unsigned short*)(ws + WS_WCOMB))[(size_t)g * 512 + h] = f2b(v);
    }
    if ((bid & 7) == 0 && t < 64) {
        int g = gt0 + t;
        float acc = bih_d[g] + bhh_d[g];
        #pragma unroll
        for (int i = 0; i < 64; ++i) acc += bout[i] * Ash[t][i];
        ((float*)(ws + WS_BCOMB))[g] = acc;
    }
}

// ---------------------------------------------------------------------------
// Main persistent kernel
// ---------------------------------------------------------------------------
__global__ void __launch_bounds__(512, 2)
vae_persistent(const float* __restrict__ seq,
               const unsigned short* __restrict__ seqb,
               const float* __restrict__ eps,
               const float* __restrict__ Wih_e,
               const float* __restrict__ Whh_e,
               const float* __restrict__ bih_e,
               const float* __restrict__ bhh_e,
               const float* __restrict__ Wmean,
               const float* __restrict__ bmean,
               const float* __restrict__ Wlv,
               const float* __restrict__ blv,
               const float* __restrict__ Winit,
               const float* __restrict__ binit,
               const float* __restrict__ Whh_d,
               const float* __restrict__ bih_d,
               const float* __restrict__ bhh_d,
               const float* __restrict__ Wout,
               const float* __restrict__ bout,
               unsigned char* __restrict__ ws,
               float* __restrict__ out)
{
    __shared__ __align__(16) short Al[16 * 520];  // staged h tile (bf16, bank-swizzled)
    __shared__ __align__(16) short Ho[512];       // h write-back staging [16][32]
    __shared__ float fbuf[128];                   // mean/logvar scratch
    __shared__ float zl[16 * 64];                 // z tile (fp32)

    const int tid  = threadIdx.x;
    const int g    = blockIdx.x & 7;        // batch group
    const int s    = blockIdx.x >> 3;       // hidden slice
    const int b0   = g * 16;
    const int lane = tid & 63;
    const int wv   = tid >> 6;
    const int col  = lane & 15;
    const int q    = lane >> 4;
    const int nloc = wv * 16 + col;
    const int gt   = nloc & 3;              // 0=i,1=f,2=g,3=o
    const int grow = gt * 512 + s * 32 + (nloc >> 2);

    uint32_t* flags = (uint32_t*)(ws + WS_FLAGS) + (size_t)g * 512;  // z only
    unsigned char* hbuf0 = ws + WS_HBUF0;
    unsigned char* hbuf1 = ws + WS_HBUF1;
    uint32_t* zbuf = (uint32_t*)(ws + WS_Z);

    float cst[4] = {0.f, 0.f, 0.f, 0.f};

    // Per-thread swizzled LDS offsets (all consumers fully unrolled -> VGPRs)
    int aoff[16];
    #pragma unroll
    for (int kt = 0; kt < 16; ++kt)
        aoff[kt] = col * 520 + alperm(kt * 4 + q) * 8;   // short index
    const int stg_b  = tid >> 5;                          // staged row
    const int stg_c  = tid & 31;                          // 32B chunk
    const int stg_u0 = alperm(stg_c * 2);                 // unit of first 16B
    // second 16B unit is stg_u0 ^ 1 (alperm keeps u>>3, 2c/2c+1 differ in bit0)

    // ---- stage round R: one-shot load, backoff poll on phase bits --------
    auto wait_and_stage = [&](uint32_t R, bool guard) {
        if (guard) __syncthreads();            // decoder: xhat still reads Al
        const unsigned char* src = (R & 1) ? hbuf1 : hbuf0;
        const uint32_t pm = phase_of(R) ? 0x40004000u : 0u;
        const unsigned char* p0 = src + (size_t)(b0 + stg_b) * 1024 + stg_c * 32;
        u32x4 v0, v1;
        uint32_t tries = 0;
        for (;;) {
            load2x16_cc(p0, p0 + 16, v0, v1);
            uint32_t bad = 0;
            #pragma unroll
            for (int i = 0; i < 4; ++i) {
                bad |= (v0[i] & 0x40004000u) ^ pm;
                bad |= (v1[i] & 0x40004000u) ^ pm;
            }
            if (bad == 0) break;               // per-lane exit: done lanes stop loading
            if (tries == 1)      __builtin_amdgcn_s_sleep(1);
            else if (tries == 2) __builtin_amdgcn_s_sleep(2);
            else if (tries == 3 || tries == 4) __builtin_amdgcn_s_sleep(4);
            else if (tries >= 5) __builtin_amdgcn_s_sleep(8);
            ++tries;
        }
        #pragma unroll
        for (int i = 0; i < 4; ++i) { v0[i] ^= pm; v1[i] ^= pm; }
        u32x4* dst = (u32x4*)Al;               // row stride 65 units (520 shorts)
        dst[stg_b * 65 + stg_u0]       = v0;
        dst[stg_b * 65 + (stg_u0 ^ 1)] = v1;
        __syncthreads();
    };

    // ---- publish round R (wave 0: phase-tagged stores, NO drain/flag) ----
    auto publish_h = [&](uint32_t R) {
        if (wv == 0) {
            unsigned char* dst = (R & 1) ? hbuf1 : hbuf0;
            const uint32_t pm = phase_of(R) ? 0x40004000u : 0u;
            int row = lane >> 2, part = lane & 3;          // 16 B per lane
            u32x4 v = ((const u32x4*)Ho)[lane];
            #pragma unroll
            for (int i = 0; i < 4; ++i) v[i] ^= pm;
            store16_cc(dst + (size_t)(b0 + row) * 1024 + s * 64 + part * 16, v);
        }
    };

    short8 wfrag[16];
    auto load_wfrag_f32 = [&](const float* Wsrc) {
        #pragma unroll
        for (int kt = 0; kt < 16; ++kt)
            wfrag[kt] = cvt8(Wsrc + (size_t)grow * 512 + kt * 32 + q * 8);
    };
    auto load_wfrag_bf16 = [&](const unsigned short* Wsrc) {
        #pragma unroll
        for (int kt = 0; kt < 16; ++kt)
            wfrag[kt] = *(const short8*)((const short*)Wsrc +
                         (size_t)grow * 512 + kt * 32 + q * 8);
    };

    // activations + cell update; h slice left in Ho (sync before publish)
    auto cell_update = [&](f32x4 acc) {
        float act[4];
        #pragma unroll
        for (int r = 0; r < 4; ++r)
            act[r] = (gt == 2) ? tanhx(acc[r]) : sigm(acc[r]);
        int base = lane & ~3;
        #pragma unroll
        for (int r = 0; r < 4; ++r) {
            float vi = __shfl(act[r], base + 0);
            float vf = __shfl(act[r], base + 1);
            float vg = __shfl(act[r], base + 2);
            float vo = __shfl(act[r], base + 3);
            cst[r] = vf * cst[r] + vi * vg;
            act[r] = vo * tanhx(cst[r]);
        }
        if (gt == 0) {
            int hd4 = wv * 4 + (col >> 2);     // 0..31
            #pragma unroll
            for (int r = 0; r < 4; ++r)
                Ho[(q * 4 + r) * 32 + hd4] = (short)f2b(act[r]);
        }
    };

    // ---------------- encoder: 512 steps ----------------
    load_wfrag_f32(Whh_e);
    short8 xwf[2];
    #pragma unroll
    for (int kt = 0; kt < 2; ++kt)
        xwf[kt] = cvt8(Wih_e + (size_t)grow * 64 + kt * 32 + q * 8);
    const float bias_e = bih_e[grow] + bhh_e[grow];

    auto load_x = [&](int t, short8* xf) {
        if (seqb) {
            const short* xs = (const short*)seqb + ((size_t)(b0 + col) * 512 + t) * 64 + q * 8;
            xf[0] = *(const short8*)(xs);
            xf[1] = *(const short8*)(xs + 32);
        } else {
            const float* xs = seq + ((size_t)(b0 + col) * 512 + t) * 64 + q * 8;
            xf[0] = cvt8(xs);
            xf[1] = cvt8(xs + 32);
        }
    };

    short8 xf[2];
    load_x(0, xf);
    for (uint32_t t = 0; t < 512; ++t) {
        // x-part first: independent of Al, overlaps the poll
        f32x4 acc = {bias_e, bias_e, bias_e, bias_e};
        acc = __builtin_amdgcn_mfma_f32_16x16x32_bf16(xf[0], xwf[0], acc, 0, 0, 0);
        acc = __builtin_amdgcn_mfma_f32_16x16x32_bf16(xf[1], xwf[1], acc, 0, 0, 0);
        if (t < 511) load_x(t + 1, xf);
        wait_and_stage(t, false);            // t=0: hbuf0 zeros, phase 0 -> instant
        #pragma unroll
        for (int kt = 0; kt < 16; ++kt) {
            short8 a = *(const short8*)(Al + aoff[kt]);
            acc = __builtin_amdgcn_mfma_f32_16x16x32_bf16(a, wfrag[kt], acc, 0, 0, 0);
        }
        cell_update(acc);
        __syncthreads();
        publish_h(t + 1);                    // h_{t+1} -> round t+1
    }

    // ---------------- VAE reparameterization (flag 513 = z ready) ---------
    wait_and_stage(512, false);              // Al = h_n
    if (tid < 128) {
        int which = tid >> 6, idx = tid & 63;
        int b = idx >> 2, ldl = idx & 3;
        int ld = s * 4 + ldl;
        const float* wrow = (which ? Wlv : Wmean) + (size_t)ld * 512;
        float a = (which ? blv[ld] : bmean[ld]);
        for (int u = 0; u < 64; ++u) {
            const short* ap = Al + b * 520 + alperm(u) * 8;
            const float* wp = wrow + u * 8;
            #pragma unroll
            for (int e = 0; e < 8; ++e)
                a += b2f((unsigned short)ap[e]) * wp[e];
        }
        out[819200 + which * 8192 + (size_t)(b0 + b) * 64 + ld] = a;
        fbuf[which * 64 + idx] = a;
    }
    __syncthreads();
    if (wv == 0) {
        int b = lane >> 2, ldl = lane & 3;
        int ld = s * 4 + ldl;
        float m = fbuf[lane], lv = fbuf[64 + lane];
        float e = eps[(size_t)(b0 + b) * 64 + ld];
        float z = m + e * __expf(0.5f * lv);
        __hip_atomic_store(zbuf + (size_t)(b0 + b) * 64 + ld,
                           __builtin_bit_cast(uint32_t, z),
                           __ATOMIC_RELAXED, __HIP_MEMORY_SCOPE_AGENT);
        drain_vm();
        if (lane == 0)
            __hip_atomic_store(&flags[s * 32], 513u,
                               __ATOMIC_RELAXED, __HIP_MEMORY_SCOPE_AGENT);
    }
    if (wv == 0 && lane < 16)
        while (__hip_atomic_load(&flags[lane * 32], __ATOMIC_RELAXED,
                                 __HIP_MEMORY_SCOPE_AGENT) < 513u) {}
    __syncthreads();

    // h_dec0 = z @ W_init^T + b_init, computed locally into Al (swizzled)
    #pragma unroll
    for (int j = 0; j < 2; ++j) {
        int idx = tid + j * 512;
        int b = idx >> 6, l = idx & 63;
        uint32_t v = __hip_atomic_load(zbuf + (size_t)(b0 + b) * 64 + l,
                                       __ATOMIC_RELAXED, __HIP_MEMORY_SCOPE_AGENT);
        zl[b * 64 + l] = __builtin_bit_cast(float, v);
    }
    __syncthreads();
    {
        int b = tid >> 5, c = tid & 31;
        #pragma unroll
        for (int j = 0; j < 16; ++j) {
            int hd = c * 16 + j;
            float a = binit[hd];
            const float* wr = Winit + (size_t)hd * 64;
            #pragma unroll
            for (int l = 0; l < 64; ++l) a += zl[b * 64 + l] * wr[l];
            Al[b * 520 + alperm(c * 2 + (j >> 3)) * 8 + (j & 7)] = (short)f2b(a);
        }
    }
    #pragma unroll
    for (int r = 0; r < 4; ++r) cst[r] = 0.f;
    __syncthreads();

    // -------- decoder: 100 steps; step d publishes h_{d+1} as R=514+d -----
    short8 wof[16];
    float xbias = 0.f;
    if (s < 4 && wv == 7) {                  // x_hat tile s on wave 7 (no duties)
        xbias = bout[s * 16 + col];
        #pragma unroll
        for (int kt = 0; kt < 16; ++kt)
            wof[kt] = cvt8(Wout + (size_t)(s * 16 + col) * 512 + kt * 32 + q * 8);
    }
    auto xhat_emit = [&](int d) {            // x_hat_d from Al (= h_{d+1})
        f32x4 a2 = {xbias, xbias, xbias, xbias};
        #pragma unroll
        for (int kt = 0; kt < 16; ++kt) {
            short8 a = *(const short8*)(Al + aoff[kt]);
            a2 = __builtin_amdgcn_mfma_f32_16x16x32_bf16(a, wof[kt], a2, 0, 0, 0);
        }
        #pragma unroll
        for (int r = 0; r < 4; ++r) {
            int b = q * 4 + r;
            out[((size_t)(b0 + b) * 100 + d) * 64 + s * 16 + col] = a2[r];
        }
    };

    load_wfrag_f32(Whh_d);                   // step 0: x0 == 0
    float bias = bih_d[grow] + bhh_d[grow];
    for (uint32_t d = 0; d < 100; ++d) {
        if (d > 0) wait_and_stage(513 + d, true);  // Al = h_d
        f32x4 acc = {bias, bias, bias, bias};
        #pragma unroll
        for (int kt = 0; kt < 16; ++kt) {
            short8 a = *(const short8*)(Al + aoff[kt]);
            acc = __builtin_amdgcn_mfma_f32_16x16x32_bf16(a, wfrag[kt], acc, 0, 0, 0);
        }
        cell_update(acc);
        __syncthreads();
        publish_h(514 + d);
        if (d >= 1 && s < 4 && wv == 7) xhat_emit(d - 1);   // off critical path
        if (d == 0) {
            load_wfrag_bf16((const unsigned short*)(ws + WS_WCOMB));
            bias = ((const float*)(ws + WS_BCOMB))[grow];
        }
    }
    wait_and_stage(613, true);               // Al = h_100
    if (s < 4 && wv == 7) xhat_emit(99);
}

extern "C" void kernel_launch(void* const* d_in, const int* in_sizes, int n_in,
                              void* d_out, int out_size, void* d_ws, size_t ws_size,
                              hipStream_t stream) {
    (void)in_sizes; (void)n_in; (void)out_size;
    const float* seq   = (const float*)d_in[0];
    const float* eps   = (const float*)d_in[2];
    const float* Wih_e = (const float*)d_in[3];
    const float* Whh_e = (const float*)d_in[4];
    const float* bih_e = (const float*)d_in[5];
    const float* bhh_e = (const float*)d_in[6];
    const float* Wmean = (const float*)d_in[7];
    const float* bmean = (const float*)d_in[8];
    const float* Wlv   = (const float*)d_in[9];
    const float* blv   = (const float*)d_in[10];
    const float* Winit = (const float*)d_in[11];
    const float* binit = (const float*)d_in[12];
    const float* Wih_d = (const float*)d_in[13];
    const float* Whh_d = (const float*)d_in[14];
    const float* bih_d = (const float*)d_in[15];
    const float* bhh_d = (const float*)d_in[16];
    const float* Wout  = (const float*)d_in[17];
    const float* bout  = (const float*)d_in[18];
    unsigned char* ws = (unsigned char*)d_ws;
    float* out = (float*)d_out;

    const bool have_seqb = ws_size >= (size_t)WS_END;
    unsigned short* seqb = have_seqb ? (unsigned short*)(ws + WS_SEQB) : nullptr;

    hipMemsetAsync(ws, 0, WS_ZERO, stream);            // flags + hbuf0 (phase 0)
    hipMemsetAsync(ws + WS_HBUF1, 0x40, HB1_SIZE, stream);  // hbuf1: bit14=1
    if (have_seqb)
        seqcvt_kernel<<<4096, 256, 0, stream>>>(seq, seqb);
    wcomb_kernel<<<256, 256, 0, stream>>>(Wih_d, Whh_d, Wout, bih_d, bhh_d, bout, ws);
    vae_persistent<<<128, 512, 0, stream>>>(
        seq, seqb, eps, Wih_e, Whh_e, bih_e, bhh_e,
        Wmean, bmean, Wlv, blv, Winit, binit,
        Whh_d, bih_d, bhh_d, Wout, bout, ws, out);
}

// Round 6
// 1731.441 us; speedup vs baseline: 1.4191x; 1.0398x over previous
//
#include <hip/hip_runtime.h>
#include <stdint.h>

// ---------------------------------------------------------------------------
// LSTM-VAE persistent kernel, MI355X (gfx950).  B=128, T=512, I=L=64, H=512,
// 100 decoder steps.  fp32 in/out; bf16 MFMA internal.
//
// 128 WGs = 8 batch-groups(g) x 16 hidden-slices(s), block=512 (8 waves).
// Slice owns 32 hidden dims = 128 interleaved gate rows [i0,f0,g0,o0,...];
// W_hh slice in 64 VGPRs/lane as MFMA B-fragments. Decoder folds x_hat via
// W_comb = W_hh_dec + W_ih_dec@W_out; x_hat tiles on wave 7 of slices 0-3.
//
// Round-14: GREEN-BASELINE RE-LAND.  After 3 straight container failures
// (r11/r12 sc0 experiments, r13 barrier-free), this is the r10 kernel that
// MEASURED 1716us/passed, plus exactly two protocol-neutral micro-opts:
//   (1) 16-deep dependent MFMA chain split into 2x8 chains merged at the
//       end (halves serial MFMA latency on the critical path).
//   (2) Ho staging stride 32 -> 36 shorts: rows {r,4+r,8+r,12+r} written
//       by the 4 q-lanes land 8 banks apart (was same-bank 4-way; part of
//       the residual 4.5e7 conflict cycles).  Publisher reads 2x 8B.
// NO sc0-only anywhere; NO XCC gating; NO barrier-free exchange.  Every
// coherent h-buffer op is the r10-proven `sc0 sc1` (LLC-served) path.
//
// Sync: POLL-ON-DATA phase-bit protocol (r9/r10, verified on hardware).
// |h|<=1 so bit14 of every bf16 is 0.  Round R writes buf[R&1] with each
// bf16 XOR'd by (phase(R) ? 0x4000 : 0); phase alternates on every reuse
// of a buffer.  Consumers poll their own 32B chunk until EVERY bf16
// carries the round's phase bit -- torn arrival keeps polling (stores are
// dword-atomic); stale-data collision impossible (stale phase is always
// the complement).  One-shot first load + s_sleep backoff on retries
// (r10's contention fix; r9's all-thread hot spin saturated the fabric).
// Overwrite safety: depth-2 transitive certification (publishing R+1
// follows staging R).  Round 513 (h_dec0) is computed locally -> decoder
// rounds >=514 use a shifted phase formula.  hbuf1 pre-filled 0x40 so
// round 1 (phase 0) cannot false-trigger on uninitialized ws.  Flags kept
// only for the one-shot fp32 z exchange (z unbounded -> no phase trick).
// ---------------------------------------------------------------------------

typedef short short8 __attribute__((ext_vector_type(8)));
typedef float f32x4 __attribute__((ext_vector_type(4)));
typedef unsigned int u32x4 __attribute__((ext_vector_type(4)));

#define WS_FLAGS  0           // 8 g x 16 s x 128 B (z exchange only)
#define WS_HBUF0  16384       // 128 KB
#define WS_HBUF1  147456      // 128 KB
#define WS_Z      278528      // 32 KB fp32
#define WS_BCOMB  311296      // 8 KB fp32
#define WS_WCOMB  319488      // 2 MB bf16
#define WS_SEQB   2416640     // 8 MB bf16 seq
#define WS_END    10805248
#define WS_ZERO   WS_HBUF1    // memset flags + hbuf0 (h0 = 0, phase 0)
#define HB1_SIZE  131072      // hbuf1: fill 0x40 (bit14=1, != phase 0)

static __device__ __forceinline__ float b2f(unsigned short u) {
    return __builtin_bit_cast(float, (unsigned int)u << 16);
}
static __device__ __forceinline__ unsigned short f2b(float f) {
    unsigned int u = __builtin_bit_cast(unsigned int, f);
    unsigned int r = u + 0x7FFFu + ((u >> 16) & 1u);  // RNE
    return (unsigned short)(r >> 16);
}
static __device__ __forceinline__ float sigm(float x)  { return 1.0f / (1.0f + __expf(-x)); }
static __device__ __forceinline__ float tanhx(float x) { return 1.0f - 2.0f / (__expf(2.0f * x) + 1.0f); }

static __device__ __forceinline__ short8 cvt8(const float* p) {
    const float4 a = ((const float4*)p)[0];
    const float4 b = ((const float4*)p)[1];
    short8 r;
    r[0] = (short)f2b(a.x); r[1] = (short)f2b(a.y);
    r[2] = (short)f2b(a.z); r[3] = (short)f2b(a.w);
    r[4] = (short)f2b(b.x); r[5] = (short)f2b(b.y);
    r[6] = (short)f2b(b.z); r[7] = (short)f2b(b.w);
    return r;
}

// phase(R): encoder/VAE rounds 0..512: (R>>1)&1.  Round 513 skipped (local
// h_dec0).  Decoder rounds 514..613 shifted so every buffer reuse still
// alternates (buf0: 512(0),514(1),516(0)..; buf1: 511(1),515(0),517(1)..).
static __device__ __forceinline__ uint32_t phase_of(uint32_t R) {
    return (R <= 512u) ? ((R >> 1) & 1u)
                       : ((((R - 513u) >> 1) & 1u) ^ 1u);
}

// LDS bank swizzle for the Al tile: 16B unit u of a row is stored at
// alperm(u).  Bijective; spreads the 8 lanes that used to share a 4-bank
// group across all 8 groups.
static __device__ __forceinline__ int alperm(int u) { return u ^ ((u >> 3) & 7); }

// --- coherent (LLC-served, L1/L2-bypass) coalesced ops: sc0 sc1 ----------
static __device__ __forceinline__ void load2x16_cc(const void* p0, const void* p1,
                                                   u32x4& v0, u32x4& v1) {
    asm volatile("global_load_dwordx4 %0, %2, off sc0 sc1\n\t"
                 "global_load_dwordx4 %1, %3, off sc0 sc1\n\t"
                 "s_waitcnt vmcnt(0)"
                 : "=&v"(v0), "=&v"(v1) : "v"(p0), "v"(p1) : "memory");
}
static __device__ __forceinline__ void store16_cc(void* p, u32x4 v) {
    asm volatile("global_store_dwordx4 %0, %1, off sc0 sc1"
                 :: "v"(p), "v"(v) : "memory");
}
static __device__ __forceinline__ void drain_vm() {
    asm volatile("s_waitcnt vmcnt(0)" ::: "memory");
}

// ---------------------------------------------------------------------------
// Prologue A: seq fp32 -> bf16
// ---------------------------------------------------------------------------
__global__ void __launch_bounds__(256)
seqcvt_kernel(const float* __restrict__ src, unsigned short* __restrict__ dst)
{
    int i = (blockIdx.x * 256 + threadIdx.x) * 4;
    float4 v = *(const float4*)(src + i);
    uint32_t lo = (uint32_t)f2b(v.x) | ((uint32_t)f2b(v.y) << 16);
    uint32_t hi = (uint32_t)f2b(v.z) | ((uint32_t)f2b(v.w) << 16);
    uint2 o; o.x = lo; o.y = hi;
    *(uint2*)(dst + i) = o;
}

// ---------------------------------------------------------------------------
// Prologue B: W_comb = W_hh_dec + W_ih_dec @ W_out (bf16 out), b_comb (fp32)
// ---------------------------------------------------------------------------
__global__ void __launch_bounds__(256)
wcomb_kernel(const float* __restrict__ Wih_d,
             const float* __restrict__ Whh_d,
             const float* __restrict__ Wout,
             const float* __restrict__ bih_d,
             const float* __restrict__ bhh_d,
             const float* __restrict__ bout,
             unsigned char* __restrict__ ws)
{
    __shared__ float Ash[64][64];
    __shared__ float Bsh[64][65];
    const int bid = blockIdx.x, t = threadIdx.x;
    const int gt0 = (bid >> 3) * 64, ht0 = (bid & 7) * 64;
    for (int j = 0; j < 16; ++j) {
        int idx = t + j * 256;
        int r = idx >> 6, c = idx & 63;
        Ash[r][c] = Wih_d[(size_t)(gt0 + r) * 64 + c];
        Bsh[r][c] = Wout[(size_t)r * 512 + ht0 + c];
    }
    __syncthreads();
    const int gl = t >> 2, hl0 = (t & 3) * 16;
    for (int hh = 0; hh < 16; ++hh) {
        float acc = 0.f;
        #pragma unroll
        for (int i = 0; i < 64; ++i) acc += Ash[gl][i] * Bsh[i][hl0 + hh];
        int g = gt0 + gl, h = ht0 + hl0 + hh;
        float v = Whh_d[(size_t)g * 512 + h] + acc;
        ((unsigned short*)(ws + WS_WCOMB))[(size_t)g * 512 + h] = f2b(v);
    }
    if ((bid & 7) == 0 && t < 64) {
        int g = gt0 + t;
        float acc = bih_d[g] + bhh_d[g];
        #pragma unroll
        for (int i = 0; i < 64; ++i) acc += bout[i] * Ash[t][i];
        ((float*)(ws + WS_BCOMB))[g] = acc;
    }
}

// ---------------------------------------------------------------------------
// Main persistent kernel
// ---------------------------------------------------------------------------
__global__ void __launch_bounds__(512, 2)
vae_persistent(const float* __restrict__ seq,
               const unsigned short* __restrict__ seqb,
               const float* __restrict__ eps,
               const float* __restrict__ Wih_e,
               const float* __restrict__ Whh_e,
               const float* __restrict__ bih_e,
               const float* __restrict__ bhh_e,
               const float* __restrict__ Wmean,
               const float* __restrict__ bmean,
               const float* __restrict__ Wlv,
               const float* __restrict__ blv,
               const float* __restrict__ Winit,
               const float* __restrict__ binit,
               const float* __restrict__ Whh_d,
               const float* __restrict__ bih_d,
               const float* __restrict__ bhh_d,
               const float* __restrict__ Wout,
               const float* __restrict__ bout,
               unsigned char* __restrict__ ws,
               float* __restrict__ out)
{
    __shared__ __align__(16) short Al[16 * 520];  // staged h tile (bf16, bank-swizzled)
    __shared__ __align__(16) short Ho[16 * 36];   // h write-back staging, stride 36
    __shared__ float fbuf[128];                   // mean/logvar scratch
    __shared__ float zl[16 * 64];                 // z tile (fp32)

    const int tid  = threadIdx.x;
    const int g    = blockIdx.x & 7;        // batch group
    const int s    = blockIdx.x >> 3;       // hidden slice
    const int b0   = g * 16;
    const int lane = tid & 63;
    const int wv   = tid >> 6;
    const int col  = lane & 15;
    const int q    = lane >> 4;
    const int nloc = wv * 16 + col;
    const int gt   = nloc & 3;              // 0=i,1=f,2=g,3=o
    const int grow = gt * 512 + s * 32 + (nloc >> 2);

    uint32_t* flags = (uint32_t*)(ws + WS_FLAGS) + (size_t)g * 512;  // z only
    unsigned char* hbuf0 = ws + WS_HBUF0;
    unsigned char* hbuf1 = ws + WS_HBUF1;
    uint32_t* zbuf = (uint32_t*)(ws + WS_Z);

    float cst[4] = {0.f, 0.f, 0.f, 0.f};

    // Per-thread swizzled LDS offsets (all consumers fully unrolled -> VGPRs)
    int aoff[16];
    #pragma unroll
    for (int kt = 0; kt < 16; ++kt)
        aoff[kt] = col * 520 + alperm(kt * 4 + q) * 8;   // short index
    const int stg_b  = tid >> 5;                          // staged row
    const int stg_c  = tid & 31;                          // 32B chunk
    const int stg_u0 = alperm(stg_c * 2);                 // unit of first 16B
    // second 16B unit is stg_u0 ^ 1

    // ---- stage round R: one-shot load, backoff poll on phase bits --------
    auto wait_and_stage = [&](uint32_t R, bool guard) {
        if (guard) __syncthreads();            // decoder: xhat still reads Al
        const unsigned char* src = (R & 1) ? hbuf1 : hbuf0;
        const uint32_t pm = phase_of(R) ? 0x40004000u : 0u;
        const unsigned char* p0 = src + (size_t)(b0 + stg_b) * 1024 + stg_c * 32;
        u32x4 v0, v1;
        uint32_t tries = 0;
        for (;;) {
            load2x16_cc(p0, p0 + 16, v0, v1);
            uint32_t bad = 0;
            #pragma unroll
            for (int i = 0; i < 4; ++i) {
                bad |= (v0[i] & 0x40004000u) ^ pm;
                bad |= (v1[i] & 0x40004000u) ^ pm;
            }
            if (bad == 0) break;               // per-lane exit
            if (tries == 1)      __builtin_amdgcn_s_sleep(1);
            else if (tries == 2) __builtin_amdgcn_s_sleep(2);
            else if (tries == 3 || tries == 4) __builtin_amdgcn_s_sleep(4);
            else if (tries >= 5) __builtin_amdgcn_s_sleep(8);
            ++tries;
        }
        #pragma unroll
        for (int i = 0; i < 4; ++i) { v0[i] ^= pm; v1[i] ^= pm; }
        u32x4* dst = (u32x4*)Al;               // row stride 65 units (520 shorts)
        dst[stg_b * 65 + stg_u0]       = v0;
        dst[stg_b * 65 + (stg_u0 ^ 1)] = v1;
        __syncthreads();
    };

    // ---- publish round R (wave 0: phase-tagged stores, NO drain/flag) ----
    auto publish_h = [&](uint32_t R) {
        if (wv == 0) {
            unsigned char* dst = (R & 1) ? hbuf1 : hbuf0;
            const uint32_t pm = phase_of(R) ? 0x40004000u : 0u;
            int row = lane >> 2, part = lane & 3;          // 16 B per lane
            const short* hp = Ho + row * 36 + part * 8;
            uint2 lo = *(const uint2*)(hp);
            uint2 hi = *(const uint2*)(hp + 4);
            u32x4 v; v[0] = lo.x; v[1] = lo.y; v[2] = hi.x; v[3] = hi.y;
            #pragma unroll
            for (int i = 0; i < 4; ++i) v[i] ^= pm;
            store16_cc(dst + (size_t)(b0 + row) * 1024 + s * 64 + part * 16, v);
        }
    };

    short8 wfrag[16];
    auto load_wfrag_f32 = [&](const float* Wsrc) {
        #pragma unroll
        for (int kt = 0; kt < 16; ++kt)
            wfrag[kt] = cvt8(Wsrc + (size_t)grow * 512 + kt * 32 + q * 8);
    };
    auto load_wfrag_bf16 = [&](const unsigned short* Wsrc) {
        #pragma unroll
        for (int kt = 0; kt < 16; ++kt)
            wfrag[kt] = *(const short8*)((const short*)Wsrc +
                         (size_t)grow * 512 + kt * 32 + q * 8);
    };

    // activations + cell update; h slice left in Ho (sync before publish)
    auto cell_update = [&](f32x4 acc) {
        float act[4];
        #pragma unroll
        for (int r = 0; r < 4; ++r)
            act[r] = (gt == 2) ? tanhx(acc[r]) : sigm(acc[r]);
        int base = lane & ~3;
        #pragma unroll
        for (int r = 0; r < 4; ++r) {
            float vi = __shfl(act[r], base + 0);
            float vf = __shfl(act[r], base + 1);
            float vg = __shfl(act[r], base + 2);
            float vo = __shfl(act[r], base + 3);
            cst[r] = vf * cst[r] + vi * vg;
            act[r] = vo * tanhx(cst[r]);
        }
        if (gt == 0) {
            int hd4 = wv * 4 + (col >> 2);     // 0..31
            #pragma unroll
            for (int r = 0; r < 4; ++r)
                Ho[(q * 4 + r) * 36 + hd4] = (short)f2b(act[r]);
        }
    };

    // ---------------- encoder: 512 steps ----------------
    load_wfrag_f32(Whh_e);
    short8 xwf[2];
    #pragma unroll
    for (int kt = 0; kt < 2; ++kt)
        xwf[kt] = cvt8(Wih_e + (size_t)grow * 64 + kt * 32 + q * 8);
    const float bias_e = bih_e[grow] + bhh_e[grow];

    auto load_x = [&](int t, short8* xf) {
        if (seqb) {
            const short* xs = (const short*)seqb + ((size_t)(b0 + col) * 512 + t) * 64 + q * 8;
            xf[0] = *(const short8*)(xs);
            xf[1] = *(const short8*)(xs + 32);
        } else {
            const float* xs = seq + ((size_t)(b0 + col) * 512 + t) * 64 + q * 8;
            xf[0] = cvt8(xs);
            xf[1] = cvt8(xs + 32);
        }
    };

    short8 xf[2];
    load_x(0, xf);
    for (uint32_t t = 0; t < 512; ++t) {
        // x-part first: independent of Al, overlaps the poll
        f32x4 acc = {bias_e, bias_e, bias_e, bias_e};
        acc = __builtin_amdgcn_mfma_f32_16x16x32_bf16(xf[0], xwf[0], acc, 0, 0, 0);
        acc = __builtin_amdgcn_mfma_f32_16x16x32_bf16(xf[1], xwf[1], acc, 0, 0, 0);
        if (t < 511) load_x(t + 1, xf);
        wait_and_stage(t, false);            // t=0: hbuf0 zeros, phase 0 -> instant
        f32x4 acc1 = {0.f, 0.f, 0.f, 0.f};   // 2 chains: halve serial MFMA latency
        #pragma unroll
        for (int kt = 0; kt < 16; kt += 2) {
            short8 a0 = *(const short8*)(Al + aoff[kt]);
            short8 a1 = *(const short8*)(Al + aoff[kt + 1]);
            acc  = __builtin_amdgcn_mfma_f32_16x16x32_bf16(a0, wfrag[kt],     acc,  0, 0, 0);
            acc1 = __builtin_amdgcn_mfma_f32_16x16x32_bf16(a1, wfrag[kt + 1], acc1, 0, 0, 0);
        }
        #pragma unroll
        for (int r = 0; r < 4; ++r) acc[r] += acc1[r];
        cell_update(acc);
        __syncthreads();
        publish_h(t + 1);                    // h_{t+1} -> round t+1
    }

    // ---------------- VAE reparameterization (flag 513 = z ready) ---------
    wait_and_stage(512, false);              // Al = h_n
    if (tid < 128) {
        int which = tid >> 6, idx = tid & 63;
        int b = idx >> 2, ldl = idx & 3;
        int ld = s * 4 + ldl;
        const float* wrow = (which ? Wlv : Wmean) + (size_t)ld * 512;
        float a = (which ? blv[ld] : bmean[ld]);
        for (int u = 0; u < 64; ++u) {
            const short* ap = Al + b * 520 + alperm(u) * 8;
            const float* wp = wrow + u * 8;
            #pragma unroll
            for (int e = 0; e < 8; ++e)
                a += b2f((unsigned short)ap[e]) * wp[e];
        }
        out[819200 + which * 8192 + (size_t)(b0 + b) * 64 + ld] = a;
        fbuf[which * 64 + idx] = a;
    }
    __syncthreads();
    if (wv == 0) {
        int b = lane >> 2, ldl = lane & 3;
        int ld = s * 4 + ldl;
        float m = fbuf[lane], lv = fbuf[64 + lane];
        float e = eps[(size_t)(b0 + b) * 64 + ld];
        float z = m + e * __expf(0.5f * lv);
        __hip_atomic_store(zbuf + (size_t)(b0 + b) * 64 + ld,
                           __builtin_bit_cast(uint32_t, z),
                           __ATOMIC_RELAXED, __HIP_MEMORY_SCOPE_AGENT);
        drain_vm();
        if (lane == 0)
            __hip_atomic_store(&flags[s * 32], 513u,
                               __ATOMIC_RELAXED, __HIP_MEMORY_SCOPE_AGENT);
    }
    if (wv == 0 && lane < 16)
        while (__hip_atomic_load(&flags[lane * 32], __ATOMIC_RELAXED,
                                 __HIP_MEMORY_SCOPE_AGENT) < 513u) {}
    __syncthreads();

    // h_dec0 = z @ W_init^T + b_init, computed locally into Al (swizzled)
    #pragma unroll
    for (int j = 0; j < 2; ++j) {
        int idx = tid + j * 512;
        int b = idx >> 6, l = idx & 63;
        uint32_t v = __hip_atomic_load(zbuf + (size_t)(b0 + b) * 64 + l,
                                       __ATOMIC_RELAXED, __HIP_MEMORY_SCOPE_AGENT);
        zl[b * 64 + l] = __builtin_bit_cast(float, v);
    }
    __syncthreads();
    {
        int b = tid >> 5, c = tid & 31;
        #pragma unroll
        for (int j = 0; j < 16; ++j) {
            int hd = c * 16 + j;
            float a = binit[hd];
            const float* wr = Winit + (size_t)hd * 64;
            #pragma unroll
            for (int l = 0; l < 64; ++l) a += zl[b * 64 + l] * wr[l];
            Al[b * 520 + alperm(c * 2 + (j >> 3)) * 8 + (j & 7)] = (short)f2b(a);
        }
    }
    #pragma unroll
    for (int r = 0; r < 4; ++r) cst[r] = 0.f;
    __syncthreads();

    // -------- decoder: 100 steps; step d publishes h_{d+1} as R=514+d -----
    short8 wof[16];
    float xbias = 0.f;
    if (s < 4 && wv == 7) {                  // x_hat tile s on wave 7 (no duties)
        xbias = bout[s * 16 + col];
        #pragma unroll
        for (int kt = 0; kt < 16; ++kt)
            wof[kt] = cvt8(Wout + (size_t)(s * 16 + col) * 512 + kt * 32 + q * 8);
    }
    auto xhat_emit = [&](int d) {            // x_hat_d from Al (= h_{d+1})
        f32x4 a2 = {xbias, xbias, xbias, xbias};
        #pragma unroll
        for (int kt = 0; kt < 16; ++kt) {
            short8 a = *(const short8*)(Al + aoff[kt]);
            a2 = __builtin_amdgcn_mfma_f32_16x16x32_bf16(a, wof[kt], a2, 0, 0, 0);
        }
        #pragma unroll
        for (int r = 0; r < 4; ++r) {
            int b = q * 4 + r;
            out[((size_t)(b0 + b) * 100 + d) * 64 + s * 16 + col] = a2[r];
        }
    };

    load_wfrag_f32(Whh_d);                   // step 0: x0 == 0
    float bias = bih_d[grow] + bhh_d[grow];
    for (uint32_t d = 0; d < 100; ++d) {
        if (d > 0) wait_and_stage(513 + d, true);  // Al = h_d
        f32x4 acc = {bias, bias, bias, bias};
        f32x4 acc1 = {0.f, 0.f, 0.f, 0.f};
        #pragma unroll
        for (int kt = 0; kt < 16; kt += 2) {
            short8 a0 = *(const short8*)(Al + aoff[kt]);
            short8 a1 = *(const short8*)(Al + aoff[kt + 1]);
            acc  = __builtin_amdgcn_mfma_f32_16x16x32_bf16(a0, wfrag[kt],     acc,  0, 0, 0);
            acc1 = __builtin_amdgcn_mfma_f32_16x16x32_bf16(a1, wfrag[kt + 1], acc1, 0, 0, 0);
        }
        #pragma unroll
        for (int r = 0; r < 4; ++r) acc[r] += acc1[r];
        cell_update(acc);
        __syncthreads();
        publish_h(514 + d);
        if (d >= 1 && s < 4 && wv == 7) xhat_emit(d - 1);   // off critical path
        if (d == 0) {
            load_wfrag_bf16((const unsigned short*)(ws + WS_WCOMB));
            bias = ((const float*)(ws + WS_BCOMB))[grow];
        }
    }
    wait_and_stage(613, true);               // Al = h_100
    if (s < 4 && wv == 7) xhat_emit(99);
}

extern "C" void kernel_launch(void* const* d_in, const int* in_sizes, int n_in,
                              void* d_out, int out_size, void* d_ws, size_t ws_size,
                              hipStream_t stream) {
    (void)in_sizes; (void)n_in; (void)out_size;
    const float* seq   = (const float*)d_in[0];
    const float* eps   = (const float*)d_in[2];
    const float* Wih_e = (const float*)d_in[3];
    const float* Whh_e = (const float*)d_in[4];
    const float* bih_e = (const float*)d_in[5];
    const float* bhh_e = (const float*)d_in[6];
    const float* Wmean = (const float*)d_in[7];
    const float* bmean = (const float*)d_in[8];
    const float* Wlv   = (const float*)d_in[9];
    const float* blv   = (const float*)d_in[10];
    const float* Winit = (const float*)d_in[11];
    const float* binit = (const float*)d_in[12];
    const float* Wih_d = (const float*)d_in[13];
    const float* Whh_d = (const float*)d_in[14];
    const float* bih_d = (const float*)d_in[15];
    const float* bhh_d = (const float*)d_in[16];
    const float* Wout  = (const float*)d_in[17];
    const float* bout  = (const float*)d_in[18];
    unsigned char* ws = (unsigned char*)d_ws;
    float* out = (float*)d_out;

    const bool have_seqb = ws_size >= (size_t)WS_END;
    unsigned short* seqb = have_seqb ? (unsigned short*)(ws + WS_SEQB) : nullptr;

    hipMemsetAsync(ws, 0, WS_ZERO, stream);            // flags + hbuf0 (phase 0)
    hipMemsetAsync(ws + WS_HBUF1, 0x40, HB1_SIZE, stream);  // hbuf1: bit14=1
    if (have_seqb)
        seqcvt_kernel<<<4096, 256, 0, stream>>>(seq, seqb);
    wcomb_kernel<<<256, 256, 0, stream>>>(Wih_d, Whh_d, Wout, bih_d, bhh_d, bout, ws);
    vae_persistent<<<128, 512, 0, stream>>>(
        seq, seqb, eps, Wih_e, Whh_e, bih_e, bhh_e,
        Wmean, bmean, Wlv, blv, Winit, binit,
        Whh_d, bih_d, bhh_d, Wout, bout, ws, out);
}